// Round 11
// baseline (1463.666 us; speedup 1.0000x reference)
//
#include <hip/hip_runtime.h>
#include <hip/hip_fp16.h>
#include <math.h>

#define NUV 200000
#define NIV 100000
#define EV  1000000
#define NQV 100000
#define NC  (3 * NIV + 3 * NUV)   // 900000 concatenated degree/bucket counters
#define EV6 (6 * EV)
// bucket layout: [rel0 items][rel1 items][rel2 items][rel0 users][rel1 users][rel2 users]

struct alignas(8) H4 { __half2 a, b; };

// ---------------- fp32 -> fp16 table conversion (both tables) ----------------
__global__ __launch_bounds__(256) void k_tohalf(const float* __restrict__ inu,
                                                const float* __restrict__ ini,
                                                __half* __restrict__ outu,
                                                __half* __restrict__ outi) {
    const int NU4 = NUV * 16;  // float4 groups in user table
    const int NTOT = NU4 + NIV * 16;
    int i = blockIdx.x * 256 + threadIdx.x;
    if (i < NTOT) {
        const float* in = (i < NU4) ? inu : ini;
        __half* out = (i < NU4) ? outu : outi;
        int j = (i < NU4) ? i : (i - NU4);
        float4 v = ((const float4*)in)[j];
        H4 o;
        o.a = __floats2half2_rn(v.x, v.y);
        o.b = __floats2half2_rn(v.z, v.w);
        ((H4*)out)[j] = o;
    }
}

// ---------------- histogram + in-bucket rank (all 3 relations) ---------------
// max per-(rel,node) degree ~40 << 65536 -> ushort ranks
__global__ __launch_bounds__(256) void k_count(const int* __restrict__ e0,
                                               const int* __restrict__ e1,
                                               const int* __restrict__ e2,
                                               int* __restrict__ cnt,
                                               unsigned short* __restrict__ rk_i,
                                               unsigned short* __restrict__ rk_u) {
    int k = blockIdx.y;
    const int* ed = (k == 0) ? e0 : (k == 1) ? e1 : e2;
    int e = blockIdx.x * 256 + threadIdx.x;
    if (e < EV) {
        int u = ed[e], i = ed[EV + e];
        rk_i[(size_t)k * EV + e] = (unsigned short)atomicAdd(&cnt[k * NIV + i], 1);
        rk_u[(size_t)k * EV + e] = (unsigned short)atomicAdd(&cnt[3 * NIV + k * NUV + u], 1);
    }
}

// ---------------- scan stage 1 (+ fused 1/sqrt(deg)) -------------------------
__global__ __launch_bounds__(256) void k_scan1(const int* __restrict__ cnt,
                                               int* __restrict__ S,
                                               int* __restrict__ bsum,
                                               float* __restrict__ invs) {
    __shared__ int tmp[256];
    int idx = blockIdx.x * 256 + threadIdx.x;
    int v = (idx < NC) ? cnt[idx] : 0;
    if (idx < NC) invs[idx] = (v > 0) ? (1.0f / sqrtf((float)v)) : 0.0f;
    tmp[threadIdx.x] = v;
    __syncthreads();
    for (int off = 1; off < 256; off <<= 1) {
        int t = (threadIdx.x >= off) ? tmp[threadIdx.x - off] : 0;
        __syncthreads();
        tmp[threadIdx.x] += t;
        __syncthreads();
    }
    if (idx < NC) S[idx] = tmp[threadIdx.x] - v;
    if (threadIdx.x == 255) bsum[blockIdx.x] = tmp[255];
}

// ---------------- scan stage 2: single-wave scan of block sums ---------------
__global__ __launch_bounds__(64) void k_scan2(int* __restrict__ bsum, int nb) {
    int lane = threadIdx.x;
    int carry = 0;
    for (int base = 0; base < nb; base += 64) {
        int i = base + lane;
        int v = (i < nb) ? bsum[i] : 0;
        int orig = v;
        #pragma unroll
        for (int off = 1; off < 64; off <<= 1) {
            int t = __shfl_up(v, off, 64);
            if (lane >= off) v += t;
        }
        if (i < nb) bsum[i] = carry + v - orig;  // exclusive
        carry += __shfl(v, 63, 64);
    }
}

// ---------------- scan stage 3: add block offsets, write sentinel ------------
__global__ __launch_bounds__(256) void k_scan3(int* __restrict__ S,
                                               const int* __restrict__ bsum) {
    int idx = blockIdx.x * 256 + threadIdx.x;
    if (idx < NC) S[idx] += bsum[blockIdx.x];
    if (idx == 0) S[NC] = EV6;
}

// ---------------- fill CSR entries via precomputed ranks (no atomics) --------
// entries are 4 B (src index only); norms reconstructed in k_agg from invs.
__global__ __launch_bounds__(256) void k_fill(const int* __restrict__ e0,
                                              const int* __restrict__ e1,
                                              const int* __restrict__ e2,
                                              const int* __restrict__ S,
                                              const unsigned short* __restrict__ rk_i,
                                              const unsigned short* __restrict__ rk_u,
                                              int* __restrict__ ent) {
    int k = blockIdx.y;
    const int* ed = (k == 0) ? e0 : (k == 1) ? e1 : e2;
    int e = blockIdx.x * 256 + threadIdx.x;
    if (e < EV) {
        int u = ed[e], i = ed[EV + e];
        ent[S[k * NIV + i] + rk_i[(size_t)k * EV + e]] = u;
        ent[S[3 * NIV + k * NUV + u] + rk_u[(size_t)k * EV + e]] = i;
    }
}

// ---------------- fused gather-aggregate + transform + hetero combine --------
// (Round-5/10 best structure.) One launch covers both directions.
// Features are fp16 rows (64 half = 128 B). Per relation k: stage W_k in LDS;
// each wave gathers its 4 dst nodes concurrently with lanes = 8 edge-subgroups
// x 8 col-lanes (16 B each); 3-level shfl_xor reduce; 256 threads = 16 rows x
// 16 col-groups compute y_k = acc @ W_k + b_k; combine across k in registers.
// Norms: per-edge invs[src] (L2-hot 4 B gather), dst factor applied once per
// node after the reduction. MODE 0: relu(max), MODE 1: sum. Output fp16.
template <int MODE>
__global__ __launch_bounds__(256, 4) void k_agg(const __half* __restrict__ x_i,  // srcs for item-side (users)
                                                const __half* __restrict__ x_u,  // srcs for user-side (items)
                                                const int* __restrict__ ent,
                                                const int* __restrict__ S,
                                                const float* __restrict__ invs,
                                                const float* __restrict__ Wall,  // [6,64,64]
                                                const float* __restrict__ ball,  // [6,64]
                                                __half* __restrict__ out_i,
                                                __half* __restrict__ out_u) {
    __shared__ float sW[4096];        // 64x64 weights for current relation
    __shared__ float sAcc[16 * 68];   // 16 rows, stride 68 (bank-conflict pad)
    const int nb_i = NIV / 16;
    bool item_side = blockIdx.x < nb_i;
    const __half* x = item_side ? x_i : x_u;
    const float* Wb = item_side ? Wall : Wall + 3 * 4096;
    const float* bb = item_side ? ball : ball + 192;
    __half* outp    = item_side ? out_i : out_u;
    int n_dst       = item_side ? NIV : NUV;
    int seg_base    = item_side ? 0 : 3 * NIV;
    int d0          = (item_side ? blockIdx.x : (blockIdx.x - nb_i)) * 16;

    int wave = threadIdx.x >> 6;
    int lane = threadIdx.x & 63;
    int eg   = lane >> 3;             // edge subgroup 0..7
    int fh   = lane & 7;              // 16-byte column group 0..7 (8 halves)
    int r2 = threadIdx.x >> 4;        // 0..15 row for transform phase
    int g  = threadIdx.x & 15;        // col group (4 cols)

    float4 res = make_float4(0.f, 0.f, 0.f, 0.f);
    for (int k = 0; k < 3; k++) {
        __syncthreads();  // protect sW/sAcc from previous iteration's readers
        // segment bounds for this wave's 4 nodes
        int idx = seg_base + k * n_dst + d0 + wave * 4;
        int v0 = S[idx], v1 = S[idx + 1], v2 = S[idx + 2], v3 = S[idx + 3], v4 = S[idx + 4];
        // src-side invs base for this (side, relation)
        int sbase = item_side ? (3 * NIV + k * NUV) : (k * NIV);
        // stage W_k
        {
            const float4* wsrc = (const float4*)(Wb + (size_t)k * 4096);
            float4* wdst = (float4*)sW;
            #pragma unroll
            for (int i = 0; i < 4; i++) wdst[threadIdx.x + 256 * i] = wsrc[threadIdx.x + 256 * i];
        }
        // gather-aggregate: 4 nodes x 8 edge-slots in flight
        {
            int st[4] = {v0, v1, v2, v3};
            int en[4] = {v1, v2, v3, v4};
            int maxlen = max(max(v1 - v0, v2 - v1), max(v3 - v2, v4 - v3));
            int maxit = (maxlen + 7) >> 3;
            float af[4][8];
            #pragma unroll
            for (int n = 0; n < 4; n++)
                #pragma unroll
                for (int j = 0; j < 8; j++) af[n][j] = 0.f;
            for (int it = 0; it < maxit; it++) {
                #pragma unroll
                for (int n = 0; n < 4; n++) {
                    int p = st[n] + (it << 3) + eg;
                    if (p < en[n]) {
                        int s = ent[p];
                        float invsrc = invs[sbase + s];
                        float4 raw = *(const float4*)(x + (size_t)s * 64 + fh * 8);
                        const __half2* h2 = (const __half2*)&raw;
                        #pragma unroll
                        for (int j = 0; j < 4; j++) {
                            float2 f = __half22float2(h2[j]);
                            af[n][2 * j]     = fmaf(f.x, invsrc, af[n][2 * j]);
                            af[n][2 * j + 1] = fmaf(f.y, invsrc, af[n][2 * j + 1]);
                        }
                    }
                }
            }
            // reduce across the 8 edge-subgroups (xor 8,16,32), apply dst factor
            #pragma unroll
            for (int n = 0; n < 4; n++) {
                #pragma unroll
                for (int j = 0; j < 8; j++) {
                    af[n][j] += __shfl_xor(af[n][j], 8, 64);
                    af[n][j] += __shfl_xor(af[n][j], 16, 64);
                    af[n][j] += __shfl_xor(af[n][j], 32, 64);
                }
                if (lane < 8) {
                    float invd = invs[idx + n];   // L2-hot, tiny live range
                    int row = wave * 4 + n;
                    *(float4*)&sAcc[row * 68 + lane * 8] =
                        make_float4(af[n][0] * invd, af[n][1] * invd,
                                    af[n][2] * invd, af[n][3] * invd);
                    *(float4*)&sAcc[row * 68 + lane * 8 + 4] =
                        make_float4(af[n][4] * invd, af[n][5] * invd,
                                    af[n][6] * invd, af[n][7] * invd);
                }
            }
        }
        __syncthreads();
        // transform: y_k = acc @ W_k + b_k for this thread's (row r2, cols g*4..+3)
        float4 y = *(const float4*)&bb[k * 64 + g * 4];
        #pragma unroll
        for (int c = 0; c < 64; c++) {
            float a = sAcc[r2 * 68 + c];
            float4 w = *(const float4*)&sW[c * 64 + g * 4];
            y.x = fmaf(a, w.x, y.x);
            y.y = fmaf(a, w.y, y.y);
            y.z = fmaf(a, w.z, y.z);
            y.w = fmaf(a, w.w, y.w);
        }
        if (k == 0) {
            res = y;
        } else if (MODE == 0) {
            res.x = fmaxf(res.x, y.x); res.y = fmaxf(res.y, y.y);
            res.z = fmaxf(res.z, y.z); res.w = fmaxf(res.w, y.w);
        } else {
            res.x += y.x; res.y += y.y; res.z += y.z; res.w += y.w;
        }
    }
    if (MODE == 0) {
        res.x = fmaxf(res.x, 0.f); res.y = fmaxf(res.y, 0.f);
        res.z = fmaxf(res.z, 0.f); res.w = fmaxf(res.w, 0.f);
    }
    H4 o;
    o.a = __floats2half2_rn(res.x, res.y);
    o.b = __floats2half2_rn(res.z, res.w);
    *(H4*)(outp + (size_t)(d0 + r2) * 64 + g * 4) = o;
}

// ---------------- decoder: 16 queries per block, tile GEMM (fp16 inputs) -----
__global__ __launch_bounds__(256) void k_decoder(const __half* __restrict__ xu,
                                                 const __half* __restrict__ xi,
                                                 const int* __restrict__ uids,
                                                 const int* __restrict__ iids,
                                                 const float* __restrict__ w1,
                                                 const float* __restrict__ b1,
                                                 const float* __restrict__ w2,
                                                 const float* __restrict__ b2,
                                                 float* __restrict__ out) {
    __shared__ float sW1[128 * 64];   // 32 KB
    __shared__ float sE[16 * 132];
    __shared__ float sH[16 * 68];
    __shared__ float sW2[64 * 4];
    {
        const float4* wsrc = (const float4*)w1;
        float4* wdst = (float4*)sW1;
        #pragma unroll
        for (int i = 0; i < 8; i++) wdst[threadIdx.x + 256 * i] = wsrc[threadIdx.x + 256 * i];
        if (threadIdx.x < 64) {
            float4 v = ((const float4*)w2)[threadIdx.x];
            ((float4*)sW2)[threadIdx.x] = v;
        }
    }
    int q0 = blockIdx.x * 16;
    {
        int q = threadIdx.x >> 4;     // 0..15
        int p = threadIdx.x & 15;     // 0..15 -> 4 halves each
        int uid = uids[q0 + q];
        int iid = iids[q0 + q];
        H4 vu = *(const H4*)(xu + (size_t)uid * 64 + p * 4);
        H4 vi = *(const H4*)(xi + (size_t)iid * 64 + p * 4);
        float2 u0 = __half22float2(vu.a), u1 = __half22float2(vu.b);
        float2 i0 = __half22float2(vi.a), i1 = __half22float2(vi.b);
        *(float4*)&sE[q * 132 + p * 4] = make_float4(u0.x, u0.y, u1.x, u1.y);
        *(float4*)&sE[q * 132 + 64 + p * 4] = make_float4(i0.x, i0.y, i1.x, i1.y);
    }
    __syncthreads();
    {
        int r = threadIdx.x >> 4;
        int g = threadIdx.x & 15;
        float4 y = *(const float4*)&b1[g * 4];
        #pragma unroll
        for (int c = 0; c < 128; c++) {
            float a = sE[r * 132 + c];
            float4 w = *(const float4*)&sW1[c * 64 + g * 4];
            y.x = fmaf(a, w.x, y.x);
            y.y = fmaf(a, w.y, y.y);
            y.z = fmaf(a, w.z, y.z);
            y.w = fmaf(a, w.w, y.w);
        }
        y.x = fmaxf(y.x, 0.f); y.y = fmaxf(y.y, 0.f);
        y.z = fmaxf(y.z, 0.f); y.w = fmaxf(y.w, 0.f);
        *(float4*)&sH[r * 68 + g * 4] = y;
    }
    __syncthreads();
    if (threadIdx.x < 64) {
        int q = threadIdx.x >> 2;
        int oc = threadIdx.x & 3;
        float acc = b2[oc];
        #pragma unroll
        for (int c = 0; c < 64; c++)
            acc = fmaf(sH[q * 68 + c], sW2[c * 4 + oc], acc);
        out[(size_t)(q0 + q) * 4 + oc] = acc;
    }
}

extern "C" void kernel_launch(void* const* d_in, const int* in_sizes, int n_in,
                              void* d_out, int out_size, void* d_ws, size_t ws_size,
                              hipStream_t stream) {
    const float* user_emb = (const float*)d_in[0];
    const float* item_emb = (const float*)d_in[1];
    const float* W1 = (const float*)d_in[2];
    const float* b1 = (const float*)d_in[3];
    const float* W2 = (const float*)d_in[4];
    const float* b2 = (const float*)d_in[5];
    const float* dw1 = (const float*)d_in[6];
    const float* db1 = (const float*)d_in[7];
    const float* dw2 = (const float*)d_in[8];
    const float* db2 = (const float*)d_in[9];
    const int* e0 = (const int*)d_in[10];
    const int* e1 = (const int*)d_in[11];
    const int* e2 = (const int*)d_in[12];
    const int* uids = (const int*)d_in[13];
    const int* iids = (const int*)d_in[14];
    float* out = (float*)d_out;
    (void)in_sizes; (void)n_in; (void)out_size; (void)ws_size;

    // workspace layout (all region sizes multiples of 16 B)
    char* base = (char*)d_ws;
    size_t off = 0;
    int*    cnt  = (int*)(base + off);    off += (size_t)NC * 4;
    int*    S    = (int*)(base + off);    off += (size_t)(NC + 8) * 4;
    int*    bsum = (int*)(base + off);    off += (size_t)4096 * 4;
    float*  invs = (float*)(base + off);  off += (size_t)NC * 4;
    unsigned short* rki = (unsigned short*)(base + off); off += (size_t)3 * EV * 2;  // 6 MB
    unsigned short* rku = (unsigned short*)(base + off); off += (size_t)3 * EV * 2;  // 6 MB
    int*    ent  = (int*)(base + off);    off += (size_t)EV6 * 4;             // 24 MB
    __half* he_u = (__half*)(base + off); off += (size_t)NUV * 64 * 2;        // 25.6 MB
    __half* he_i = (__half*)(base + off); off += (size_t)NIV * 64 * 2;        // 12.8 MB
    __half* xu1h = (__half*)(base + off); off += (size_t)NUV * 64 * 2;
    __half* xi1h = (__half*)(base + off); off += (size_t)NIV * 64 * 2;
    __half* xu2h = (__half*)(base + off); off += (size_t)NUV * 64 * 2;
    __half* xi2h = (__half*)(base + off); off += (size_t)NIV * 64 * 2;

    const int EB  = (EV + 255) / 256;       // 3907
    const int SB1 = (NC + 255) / 256;       // 3516
    const int AGGB = NIV / 16 + NUV / 16;   // 18750
    const int THB = ((NUV + NIV) * 16 + 255) / 256;

    // ---- fp16 feature tables ----
    k_tohalf<<<THB, 256, 0, stream>>>(user_emb, item_emb, he_u, he_i);

    // ---- CSR build ----
    hipMemsetAsync(cnt, 0, (size_t)NC * 4, stream);
    k_count<<<dim3(EB, 3), 256, 0, stream>>>(e0, e1, e2, cnt, rki, rku);
    k_scan1<<<SB1, 256, 0, stream>>>(cnt, S, bsum, invs);
    k_scan2<<<1, 64, 0, stream>>>(bsum, SB1);
    k_scan3<<<SB1, 256, 0, stream>>>(S, bsum);
    k_fill<<<dim3(EB, 3), 256, 0, stream>>>(e0, e1, e2, S, rki, rku, ent);

    // ---- layer 1 (max across relations, then relu): both directions ----
    k_agg<0><<<AGGB, 256, 0, stream>>>(he_u, he_i, ent, S, invs, W1, b1, xi1h, xu1h);
    // ---- layer 2 (sum across relations): both directions ----
    k_agg<1><<<AGGB, 256, 0, stream>>>(xu1h, xi1h, ent, S, invs, W2, b2, xi2h, xu2h);

    // ---- decoder (fp16 inputs) ----
    k_decoder<<<NQV / 16, 256, 0, stream>>>(xu2h, xi2h, uids, iids,
                                            dw1, db1, dw2, db2, out);
}

// Round 12
// 1423.157 us; speedup vs baseline: 1.0285x; 1.0285x over previous
//
#include <hip/hip_runtime.h>
#include <hip/hip_fp16.h>
#include <math.h>

#define NUV 200000
#define NIV 100000
#define EV  1000000
#define NQV 100000
#define NC  (3 * NIV + 3 * NUV)   // 900000 concatenated degree/bucket counters
#define EV6 (6 * EV)
// bucket layout: [rel0 items][rel1 items][rel2 items][rel0 users][rel1 users][rel2 users]

struct alignas(8) H4 { __half2 a, b; };

// ---------------- fp32 -> fp16 table conversion (both tables) ----------------
__global__ __launch_bounds__(256) void k_tohalf(const float* __restrict__ inu,
                                                const float* __restrict__ ini,
                                                __half* __restrict__ outu,
                                                __half* __restrict__ outi) {
    const int NU4 = NUV * 16;  // float4 groups in user table
    const int NTOT = NU4 + NIV * 16;
    int i = blockIdx.x * 256 + threadIdx.x;
    if (i < NTOT) {
        const float* in = (i < NU4) ? inu : ini;
        __half* out = (i < NU4) ? outu : outi;
        int j = (i < NU4) ? i : (i - NU4);
        float4 v = ((const float4*)in)[j];
        H4 o;
        o.a = __floats2half2_rn(v.x, v.y);
        o.b = __floats2half2_rn(v.z, v.w);
        ((H4*)out)[j] = o;
    }
}

// ---------------- histogram + in-bucket rank (all 3 relations) ---------------
// max per-(rel,node) degree ~40 << 65536 -> ushort ranks (halves rank traffic)
__global__ __launch_bounds__(256) void k_count(const int* __restrict__ e0,
                                               const int* __restrict__ e1,
                                               const int* __restrict__ e2,
                                               int* __restrict__ cnt,
                                               unsigned short* __restrict__ rk_i,
                                               unsigned short* __restrict__ rk_u) {
    int k = blockIdx.y;
    const int* ed = (k == 0) ? e0 : (k == 1) ? e1 : e2;
    int e = blockIdx.x * 256 + threadIdx.x;
    if (e < EV) {
        int u = ed[e], i = ed[EV + e];
        rk_i[(size_t)k * EV + e] = (unsigned short)atomicAdd(&cnt[k * NIV + i], 1);
        rk_u[(size_t)k * EV + e] = (unsigned short)atomicAdd(&cnt[3 * NIV + k * NUV + u], 1);
    }
}

// ---------------- scan stage 1 (+ fused 1/sqrt(deg)) -------------------------
__global__ __launch_bounds__(256) void k_scan1(const int* __restrict__ cnt,
                                               int* __restrict__ S,
                                               int* __restrict__ bsum,
                                               float* __restrict__ invs) {
    __shared__ int tmp[256];
    int idx = blockIdx.x * 256 + threadIdx.x;
    int v = (idx < NC) ? cnt[idx] : 0;
    if (idx < NC) invs[idx] = (v > 0) ? (1.0f / sqrtf((float)v)) : 0.0f;
    tmp[threadIdx.x] = v;
    __syncthreads();
    for (int off = 1; off < 256; off <<= 1) {
        int t = (threadIdx.x >= off) ? tmp[threadIdx.x - off] : 0;
        __syncthreads();
        tmp[threadIdx.x] += t;
        __syncthreads();
    }
    if (idx < NC) S[idx] = tmp[threadIdx.x] - v;
    if (threadIdx.x == 255) bsum[blockIdx.x] = tmp[255];
}

// ---------------- scan stage 2: single-wave scan of block sums ---------------
__global__ __launch_bounds__(64) void k_scan2(int* __restrict__ bsum, int nb) {
    int lane = threadIdx.x;
    int carry = 0;
    for (int base = 0; base < nb; base += 64) {
        int i = base + lane;
        int v = (i < nb) ? bsum[i] : 0;
        int orig = v;
        #pragma unroll
        for (int off = 1; off < 64; off <<= 1) {
            int t = __shfl_up(v, off, 64);
            if (lane >= off) v += t;
        }
        if (i < nb) bsum[i] = carry + v - orig;  // exclusive
        carry += __shfl(v, 63, 64);
    }
}

// ---------------- scan stage 3: add block offsets, write sentinel ------------
__global__ __launch_bounds__(256) void k_scan3(int* __restrict__ S,
                                               const int* __restrict__ bsum) {
    int idx = blockIdx.x * 256 + threadIdx.x;
    if (idx < NC) S[idx] += bsum[blockIdx.x];
    if (idx == 0) S[NC] = EV6;
}

// ---------------- fill CSR entries via precomputed ranks (no atomics) --------
__global__ __launch_bounds__(256) void k_fill(const int* __restrict__ e0,
                                              const int* __restrict__ e1,
                                              const int* __restrict__ e2,
                                              const float* __restrict__ invs,
                                              const int* __restrict__ S,
                                              const unsigned short* __restrict__ rk_i,
                                              const unsigned short* __restrict__ rk_u,
                                              float2* __restrict__ ent) {
    int k = blockIdx.y;
    const int* ed = (k == 0) ? e0 : (k == 1) ? e1 : e2;
    int e = blockIdx.x * 256 + threadIdx.x;
    if (e < EV) {
        int u = ed[e], i = ed[EV + e];
        float nm = invs[k * NIV + i] * invs[3 * NIV + k * NUV + u];
        int p1 = S[k * NIV + i] + rk_i[(size_t)k * EV + e];
        ent[p1] = make_float2(__int_as_float(u), nm);
        int p2 = S[3 * NIV + k * NUV + u] + rk_u[(size_t)k * EV + e];
        ent[p2] = make_float2(__int_as_float(i), nm);
    }
}

// ---------------- fused gather-aggregate + transform + hetero combine --------
// (Round-5/10 best structure, unchanged.) One launch covers both directions.
// Features are fp16 rows (64 half = 128 B). Per relation k: stage W_k in LDS;
// each wave gathers its 4 dst nodes concurrently with lanes = 8 edge-subgroups
// x 8 col-lanes (16 B each) -> ~32 row loads nominal in flight per wave;
// 3-level shfl_xor reduce; 256 threads = 16 rows x 16 col-groups compute
// y_k = acc @ W_k + b_k; combine across k in registers.
// MODE 0: relu(max), MODE 1: sum. HOUT: fp16 out else fp32.
template <int MODE, bool HOUT>
__global__ __launch_bounds__(256, 4) void k_agg(const __half* __restrict__ x_i,  // srcs for item-side (users)
                                                const __half* __restrict__ x_u,  // srcs for user-side (items)
                                                const float2* __restrict__ ent,
                                                const int* __restrict__ S,
                                                const float* __restrict__ Wall,  // [6,64,64]
                                                const float* __restrict__ ball,  // [6,64]
                                                void* __restrict__ out_i,
                                                void* __restrict__ out_u) {
    __shared__ float sW[4096];        // 64x64 weights for current relation
    __shared__ float sAcc[16 * 68];   // 16 rows, stride 68 (bank-conflict pad)
    const int nb_i = NIV / 16;
    bool item_side = blockIdx.x < nb_i;
    const __half* x = item_side ? x_i : x_u;
    const float* Wb = item_side ? Wall : Wall + 3 * 4096;
    const float* bb = item_side ? ball : ball + 192;
    void* outp      = item_side ? out_i : out_u;
    int n_dst       = item_side ? NIV : NUV;
    int seg_base    = item_side ? 0 : 3 * NIV;
    int d0          = (item_side ? blockIdx.x : (blockIdx.x - nb_i)) * 16;

    int wave = threadIdx.x >> 6;
    int lane = threadIdx.x & 63;
    int eg   = lane >> 3;             // edge subgroup 0..7
    int fh   = lane & 7;              // 16-byte column group 0..7 (8 halves)
    int r2 = threadIdx.x >> 4;        // 0..15 row for transform phase
    int g  = threadIdx.x & 15;        // col group (4 cols)

    float4 res = make_float4(0.f, 0.f, 0.f, 0.f);
    for (int k = 0; k < 3; k++) {
        __syncthreads();  // protect sW/sAcc from previous iteration's readers
        // segment bounds for this wave's 4 nodes
        int idx = seg_base + k * n_dst + d0 + wave * 4;
        int v0 = S[idx], v1 = S[idx + 1], v2 = S[idx + 2], v3 = S[idx + 3], v4 = S[idx + 4];
        // stage W_k
        {
            const float4* wsrc = (const float4*)(Wb + (size_t)k * 4096);
            float4* wdst = (float4*)sW;
            #pragma unroll
            for (int i = 0; i < 4; i++) wdst[threadIdx.x + 256 * i] = wsrc[threadIdx.x + 256 * i];
        }
        // gather-aggregate: 4 nodes x 8 edge-slots in flight
        {
            int st[4] = {v0, v1, v2, v3};
            int en[4] = {v1, v2, v3, v4};
            int maxlen = max(max(v1 - v0, v2 - v1), max(v3 - v2, v4 - v3));
            int maxit = (maxlen + 7) >> 3;
            float af[4][8];
            #pragma unroll
            for (int n = 0; n < 4; n++)
                #pragma unroll
                for (int j = 0; j < 8; j++) af[n][j] = 0.f;
            for (int it = 0; it < maxit; it++) {
                #pragma unroll
                for (int n = 0; n < 4; n++) {
                    int p = st[n] + (it << 3) + eg;
                    if (p < en[n]) {
                        float2 e = ent[p];
                        int s = __float_as_int(e.x);
                        float4 raw = *(const float4*)(x + (size_t)s * 64 + fh * 8);
                        const __half2* h2 = (const __half2*)&raw;
                        #pragma unroll
                        for (int j = 0; j < 4; j++) {
                            float2 f = __half22float2(h2[j]);
                            af[n][2 * j]     = fmaf(f.x, e.y, af[n][2 * j]);
                            af[n][2 * j + 1] = fmaf(f.y, e.y, af[n][2 * j + 1]);
                        }
                    }
                }
            }
            // reduce across the 8 edge-subgroups (xor 8,16,32)
            #pragma unroll
            for (int n = 0; n < 4; n++) {
                #pragma unroll
                for (int j = 0; j < 8; j++) {
                    af[n][j] += __shfl_xor(af[n][j], 8, 64);
                    af[n][j] += __shfl_xor(af[n][j], 16, 64);
                    af[n][j] += __shfl_xor(af[n][j], 32, 64);
                }
                if (lane < 8) {
                    int row = wave * 4 + n;
                    *(float4*)&sAcc[row * 68 + lane * 8] =
                        make_float4(af[n][0], af[n][1], af[n][2], af[n][3]);
                    *(float4*)&sAcc[row * 68 + lane * 8 + 4] =
                        make_float4(af[n][4], af[n][5], af[n][6], af[n][7]);
                }
            }
        }
        __syncthreads();
        // transform: y_k = acc @ W_k + b_k for this thread's (row r2, cols g*4..+3)
        float4 y = *(const float4*)&bb[k * 64 + g * 4];
        #pragma unroll
        for (int c = 0; c < 64; c++) {
            float a = sAcc[r2 * 68 + c];
            float4 w = *(const float4*)&sW[c * 64 + g * 4];
            y.x = fmaf(a, w.x, y.x);
            y.y = fmaf(a, w.y, y.y);
            y.z = fmaf(a, w.z, y.z);
            y.w = fmaf(a, w.w, y.w);
        }
        if (k == 0) {
            res = y;
        } else if (MODE == 0) {
            res.x = fmaxf(res.x, y.x); res.y = fmaxf(res.y, y.y);
            res.z = fmaxf(res.z, y.z); res.w = fmaxf(res.w, y.w);
        } else {
            res.x += y.x; res.y += y.y; res.z += y.z; res.w += y.w;
        }
    }
    if (MODE == 0) {
        res.x = fmaxf(res.x, 0.f); res.y = fmaxf(res.y, 0.f);
        res.z = fmaxf(res.z, 0.f); res.w = fmaxf(res.w, 0.f);
    }
    if (HOUT) {
        H4 o;
        o.a = __floats2half2_rn(res.x, res.y);
        o.b = __floats2half2_rn(res.z, res.w);
        *(H4*)((__half*)outp + (size_t)(d0 + r2) * 64 + g * 4) = o;
    } else {
        *(float4*)((float*)outp + (size_t)(d0 + r2) * 64 + g * 4) = res;
    }
}

// ---------------- decoder: 16 queries per block, tile GEMM (fp16 inputs) -----
__global__ __launch_bounds__(256) void k_decoder(const __half* __restrict__ xu,
                                                 const __half* __restrict__ xi,
                                                 const int* __restrict__ uids,
                                                 const int* __restrict__ iids,
                                                 const float* __restrict__ w1,
                                                 const float* __restrict__ b1,
                                                 const float* __restrict__ w2,
                                                 const float* __restrict__ b2,
                                                 float* __restrict__ out) {
    __shared__ float sW1[128 * 64];   // 32 KB
    __shared__ float sE[16 * 132];
    __shared__ float sH[16 * 68];
    __shared__ float sW2[64 * 4];
    {
        const float4* wsrc = (const float4*)w1;
        float4* wdst = (float4*)sW1;
        #pragma unroll
        for (int i = 0; i < 8; i++) wdst[threadIdx.x + 256 * i] = wsrc[threadIdx.x + 256 * i];
        if (threadIdx.x < 64) {
            float4 v = ((const float4*)w2)[threadIdx.x];
            ((float4*)sW2)[threadIdx.x] = v;
        }
    }
    int q0 = blockIdx.x * 16;
    {
        int q = threadIdx.x >> 4;     // 0..15
        int p = threadIdx.x & 15;     // 0..15 -> 4 halves each
        int uid = uids[q0 + q];
        int iid = iids[q0 + q];
        H4 vu = *(const H4*)(xu + (size_t)uid * 64 + p * 4);
        H4 vi = *(const H4*)(xi + (size_t)iid * 64 + p * 4);
        float2 u0 = __half22float2(vu.a), u1 = __half22float2(vu.b);
        float2 i0 = __half22float2(vi.a), i1 = __half22float2(vi.b);
        *(float4*)&sE[q * 132 + p * 4] = make_float4(u0.x, u0.y, u1.x, u1.y);
        *(float4*)&sE[q * 132 + 64 + p * 4] = make_float4(i0.x, i0.y, i1.x, i1.y);
    }
    __syncthreads();
    {
        int r = threadIdx.x >> 4;
        int g = threadIdx.x & 15;
        float4 y = *(const float4*)&b1[g * 4];
        #pragma unroll
        for (int c = 0; c < 128; c++) {
            float a = sE[r * 132 + c];
            float4 w = *(const float4*)&sW1[c * 64 + g * 4];
            y.x = fmaf(a, w.x, y.x);
            y.y = fmaf(a, w.y, y.y);
            y.z = fmaf(a, w.z, y.z);
            y.w = fmaf(a, w.w, y.w);
        }
        y.x = fmaxf(y.x, 0.f); y.y = fmaxf(y.y, 0.f);
        y.z = fmaxf(y.z, 0.f); y.w = fmaxf(y.w, 0.f);
        *(float4*)&sH[r * 68 + g * 4] = y;
    }
    __syncthreads();
    if (threadIdx.x < 64) {
        int q = threadIdx.x >> 2;
        int oc = threadIdx.x & 3;
        float acc = b2[oc];
        #pragma unroll
        for (int c = 0; c < 64; c++)
            acc = fmaf(sH[q * 68 + c], sW2[c * 4 + oc], acc);
        out[(size_t)(q0 + q) * 4 + oc] = acc;
    }
}

extern "C" void kernel_launch(void* const* d_in, const int* in_sizes, int n_in,
                              void* d_out, int out_size, void* d_ws, size_t ws_size,
                              hipStream_t stream) {
    const float* user_emb = (const float*)d_in[0];
    const float* item_emb = (const float*)d_in[1];
    const float* W1 = (const float*)d_in[2];
    const float* b1 = (const float*)d_in[3];
    const float* W2 = (const float*)d_in[4];
    const float* b2 = (const float*)d_in[5];
    const float* dw1 = (const float*)d_in[6];
    const float* db1 = (const float*)d_in[7];
    const float* dw2 = (const float*)d_in[8];
    const float* db2 = (const float*)d_in[9];
    const int* e0 = (const int*)d_in[10];
    const int* e1 = (const int*)d_in[11];
    const int* e2 = (const int*)d_in[12];
    const int* uids = (const int*)d_in[13];
    const int* iids = (const int*)d_in[14];
    float* out = (float*)d_out;
    (void)in_sizes; (void)n_in; (void)out_size; (void)ws_size;

    // workspace layout (all region sizes multiples of 16 B)
    char* base = (char*)d_ws;
    size_t off = 0;
    int*    cnt  = (int*)(base + off);    off += (size_t)NC * 4;
    int*    S    = (int*)(base + off);    off += (size_t)(NC + 8) * 4;
    int*    bsum = (int*)(base + off);    off += (size_t)4096 * 4;
    float*  invs = (float*)(base + off);  off += (size_t)NC * 4;
    unsigned short* rki = (unsigned short*)(base + off); off += (size_t)3 * EV * 2;  // 6 MB
    unsigned short* rku = (unsigned short*)(base + off); off += (size_t)3 * EV * 2;  // 6 MB
    float2* ent  = (float2*)(base + off); off += (size_t)EV6 * 8;             // 48 MB
    __half* he_u = (__half*)(base + off); off += (size_t)NUV * 64 * 2;        // 25.6 MB
    __half* he_i = (__half*)(base + off); off += (size_t)NIV * 64 * 2;        // 12.8 MB
    __half* xu1h = (__half*)(base + off); off += (size_t)NUV * 64 * 2;
    __half* xi1h = (__half*)(base + off); off += (size_t)NIV * 64 * 2;
    __half* xu2h = (__half*)(base + off); off += (size_t)NUV * 64 * 2;
    __half* xi2h = (__half*)(base + off); off += (size_t)NIV * 64 * 2;

    const int EB  = (EV + 255) / 256;       // 3907
    const int SB1 = (NC + 255) / 256;       // 3516
    const int AGGB = NIV / 16 + NUV / 16;   // 18750
    const int THB = ((NUV + NIV) * 16 + 255) / 256;

    // ---- fp16 feature tables ----
    k_tohalf<<<THB, 256, 0, stream>>>(user_emb, item_emb, he_u, he_i);

    // ---- CSR build ----
    hipMemsetAsync(cnt, 0, (size_t)NC * 4, stream);
    k_count<<<dim3(EB, 3), 256, 0, stream>>>(e0, e1, e2, cnt, rki, rku);
    k_scan1<<<SB1, 256, 0, stream>>>(cnt, S, bsum, invs);
    k_scan2<<<1, 64, 0, stream>>>(bsum, SB1);
    k_scan3<<<SB1, 256, 0, stream>>>(S, bsum);
    k_fill<<<dim3(EB, 3), 256, 0, stream>>>(e0, e1, e2, invs, S, rki, rku, ent);

    // ---- layer 1 (max across relations, then relu): both directions ----
    k_agg<0, true><<<AGGB, 256, 0, stream>>>(he_u, he_i, ent, S, W1, b1, xi1h, xu1h);
    // ---- layer 2 (sum across relations): both directions, fp16 out ----
    k_agg<1, true><<<AGGB, 256, 0, stream>>>(xu1h, xi1h, ent, S, W2, b2, xi2h, xu2h);

    // ---- decoder (fp16 inputs) ----
    k_decoder<<<NQV / 16, 256, 0, stream>>>(xu2h, xi2h, uids, iids,
                                            dw1, db1, dw2, db2, out);
}